// Round 1
// baseline (525.512 us; speedup 1.0000x reference)
//
#include <hip/hip_runtime.h>
#include <hip/hip_bf16.h>
#include <stdint.h>

#define IN_F   16080
#define NTREES 64
#define NLEAF  128
#define NCLS   16
#define NBATCH 64
#define M_TOT  (NBATCH*NTREES)     // 4096
#define OUT_HALF (M_TOT*NLEAF)     // 524288

#define BM 64
#define BN 128
#define BK 32
#define KSPLIT 8
#define NSTEPS ((IN_F + BK - 1)/BK)   // 503 (502 full + 16-tail, zero-padded)
#define LDS_STRIDE 40                 // 32 + 8 bf16 pad -> 80B row stride, 16B aligned

typedef __attribute__((ext_vector_type(8))) short short8;   // 8 x bf16 (4 VGPRs)
typedef __attribute__((ext_vector_type(4))) float f32x4;

// round-to-nearest-even fp32 -> bf16, packed pair
__device__ __forceinline__ uint32_t pack_bf16x2(float lo, float hi){
  uint32_t a = __builtin_bit_cast(uint32_t, lo);
  uint32_t b = __builtin_bit_cast(uint32_t, hi);
  a = (a + 0x7fffu + ((a >> 16) & 1u)) >> 16;          // low 16 bits
  b = (b + 0x7fffu + ((b >> 16) & 1u)) & 0xffff0000u;  // high 16 bits
  return a | b;
}

// C = X[4096,16080] * W[128,16080]^T, split-K partial sums atomically
// accumulated into accbuf[4096][128] (pre-zeroed).
__global__ __launch_bounds__(256, 2)
void gemm_split_kernel(const float* __restrict__ X,
                       const float* __restrict__ Wg,
                       float* __restrict__ accbuf){
  __shared__ __align__(16) uint16_t As[BM * LDS_STRIDE];   // 5120 B
  __shared__ __align__(16) uint16_t Bs[BN * LDS_STRIDE];   // 10240 B

  const int tid = threadIdx.x;
  const int m0  = blockIdx.x * BM;
  const int kc  = blockIdx.y;
  const int s0  = (kc * NSTEPS) / KSPLIT;
  const int s1  = ((kc + 1) * NSTEPS) / KSPLIT;

  const int lane = tid & 63;
  const int wv   = tid >> 6;      // wave 0..3 -> 16-row m-slice
  const int fr   = lane & 15;     // row/col index within 16x16 tile
  const int fq   = lane >> 4;     // k-quad: 8 consecutive k at fq*8

  f32x4 acc[8];
  #pragma unroll
  for (int i = 0; i < 8; ++i) acc[i] = (f32x4){0.f, 0.f, 0.f, 0.f};

  for (int s = s0; s < s1; ++s){
    const int k0 = s * BK;
    __syncthreads();   // previous tile's readers done before we overwrite

    // Stage A-tile: 64 rows x 32 k, fp32 -> bf16. 512 float4 chunks, 2/thread.
    #pragma unroll
    for (int j = 0; j < 2; ++j){
      int lin = tid + j * 256;
      int r   = lin >> 3;
      int c4  = (lin & 7) << 2;
      int gk  = k0 + c4;
      float x0 = 0.f, x1 = 0.f, x2 = 0.f, x3 = 0.f;
      if (gk + 4 <= IN_F){            // K % 4 == 0, so tail chunks are all-or-nothing
        const float4* p = (const float4*)(X + (size_t)(m0 + r) * IN_F + gk);
        float4 v = *p;
        x0 = v.x; x1 = v.y; x2 = v.z; x3 = v.w;
      }
      *(uint2*)&As[r * LDS_STRIDE + c4] =
          make_uint2(pack_bf16x2(x0, x1), pack_bf16x2(x2, x3));
    }
    // Stage W-tile: 128 rows x 32 k. 1024 chunks, 4/thread.
    #pragma unroll
    for (int j = 0; j < 4; ++j){
      int lin = tid + j * 256;
      int r   = lin >> 3;
      int c4  = (lin & 7) << 2;
      int gk  = k0 + c4;
      float x0 = 0.f, x1 = 0.f, x2 = 0.f, x3 = 0.f;
      if (gk + 4 <= IN_F){
        const float4* p = (const float4*)(Wg + (size_t)r * IN_F + gk);
        float4 v = *p;
        x0 = v.x; x1 = v.y; x2 = v.z; x3 = v.w;
      }
      *(uint2*)&Bs[r * LDS_STRIDE + c4] =
          make_uint2(pack_bf16x2(x0, x1), pack_bf16x2(x2, x3));
    }
    __syncthreads();

    // A-frag: lane holds A[m = fr][k = fq*8 + j], j=0..7 (16B aligned: stride 80B, off fq*16)
    short8 a = *(const short8*)&As[(wv * 16 + fr) * LDS_STRIDE + fq * 8];
    #pragma unroll
    for (int nt = 0; nt < 8; ++nt){
      short8 b = *(const short8*)&Bs[(nt * 16 + fr) * LDS_STRIDE + fq * 8];
      acc[nt] = __builtin_amdgcn_mfma_f32_16x16x32_bf16(a, b, acc[nt], 0, 0, 0);
    }
  }

  // C/D layout: col = lane&15, row = (lane>>4)*4 + reg  [m89-verified]
  const int rbase = m0 + wv * 16 + fq * 4;
  #pragma unroll
  for (int nt = 0; nt < 8; ++nt){
    int col = nt * 16 + fr;
    #pragma unroll
    for (int r = 0; r < 4; ++r){
      atomicAdd(&accbuf[(size_t)(rbase + r) * NLEAF + col], acc[nt][r]);
    }
  }
}

// In-place: out[idx] holds raw GEMM sum; add bias, hardtanh, then 16-class
// softmax Gini into out[OUT_HALF + idx].
__global__ __launch_bounds__(256)
void epilogue_kernel(float* __restrict__ out,
                     const float* __restrict__ bias,
                     const float* __restrict__ contrib){
  int idx = blockIdx.x * 256 + threadIdx.x;   // < OUT_HALF
  int l   = idx & (NLEAF - 1);
  int row = idx >> 7;
  int t   = row & (NTREES - 1);

  float s = out[idx] + bias[l];
  s = fminf(1.f, fmaxf(-1.f, s));
  out[idx] = s;

  const float4* cp = (const float4*)(contrib + (((size_t)t * NLEAF + l) << 4));
  float4 c0 = cp[0], c1 = cp[1], c2 = cp[2], c3 = cp[3];
  float v[16] = { s*c0.x, s*c0.y, s*c0.z, s*c0.w,
                  s*c1.x, s*c1.y, s*c1.z, s*c1.w,
                  s*c2.x, s*c2.y, s*c2.z, s*c2.w,
                  s*c3.x, s*c3.y, s*c3.z, s*c3.w };
  float m = v[0];
  #pragma unroll
  for (int c = 1; c < 16; ++c) m = fmaxf(m, v[c]);
  float se = 0.f, se2 = 0.f;
  #pragma unroll
  for (int c = 0; c < 16; ++c){
    float e = __expf(v[c] - m);
    se  += e;
    se2 += e * e;
  }
  out[OUT_HALF + idx] = (float)NCLS - se2 / (se * se);
}

extern "C" void kernel_launch(void* const* d_in, const int* in_sizes, int n_in,
                              void* d_out, int out_size, void* d_ws, size_t ws_size,
                              hipStream_t stream){
  const float* X       = (const float*)d_in[0];   // [64,64,16080]
  const float* Wg      = (const float*)d_in[1];   // [128,16080]
  const float* bias    = (const float*)d_in[2];   // [128]
  const float* contrib = (const float*)d_in[3];   // [64,128,16]
  float* out = (float*)d_out;

  // zero the accumulator region (first output half); capturable async memset
  hipMemsetAsync(out, 0, (size_t)OUT_HALF * sizeof(float), stream);

  dim3 g1(M_TOT / BM, KSPLIT);
  gemm_split_kernel<<<g1, 256, 0, stream>>>(X, Wg, out);

  epilogue_kernel<<<OUT_HALF / 256, 256, 0, stream>>>(out, bias, contrib);
}

// Round 2
// 444.032 us; speedup vs baseline: 1.1835x; 1.1835x over previous
//
#include <hip/hip_runtime.h>
#include <hip/hip_bf16.h>
#include <stdint.h>

#define IN_F   16080
#define NTREES 64
#define NLEAF  128
#define NCLS   16
#define NBATCH 64
#define M_TOT  (NBATCH*NTREES)     // 4096
#define OUT_HALF (M_TOT*NLEAF)     // 524288

#define BM 64
#define BN 128
#define BK 64
#define KSPLIT 16
#define NSTEPS ((IN_F + BK - 1)/BK)   // 252 (251 full + 16-elem tail, zero-padded)
#define LDS_STRIDE 72                 // 64 + 8 bf16 pad -> 144B row stride (16B aligned,
                                      // rotates banks by 4/row -> 2-way alias = free)

typedef __attribute__((ext_vector_type(8))) short short8;   // 8 x bf16 (4 VGPRs)
typedef __attribute__((ext_vector_type(4))) float f32x4;

// round-to-nearest-even fp32 -> bf16, packed pair
__device__ __forceinline__ uint32_t pack_bf16x2(float lo, float hi){
  uint32_t a = __builtin_bit_cast(uint32_t, lo);
  uint32_t b = __builtin_bit_cast(uint32_t, hi);
  a = (a + 0x7fffu + ((a >> 16) & 1u)) >> 16;          // low 16 bits
  b = (b + 0x7fffu + ((b >> 16) & 1u)) & 0xffff0000u;  // high 16 bits
  return a | b;
}

// C = X[4096,16080] * W[128,16080]^T, split-K partials atomically
// accumulated into accbuf[4096][128] (pre-zeroed).
__global__ __launch_bounds__(256, 4)
void gemm_split_kernel(const float* __restrict__ X,
                       const float* __restrict__ Wg,
                       float* __restrict__ accbuf){
  __shared__ __align__(16) uint16_t As[BM * LDS_STRIDE];   //  9216 B
  __shared__ __align__(16) uint16_t Bs[BN * LDS_STRIDE];   // 18432 B

  const int tid = threadIdx.x;
  const int m0  = blockIdx.x * BM;
  const int kc  = blockIdx.y;
  const int s0  = (kc * NSTEPS) / KSPLIT;
  const int s1  = ((kc + 1) * NSTEPS) / KSPLIT;

  const int lane = tid & 63;
  const int wv   = tid >> 6;      // wave 0..3 -> 16-row m-slice
  const int fr   = lane & 15;     // row/col index within 16x16 tile
  const int fq   = lane >> 4;     // k-quad: 8 consecutive k at fq*8

  f32x4 acc[8];
  #pragma unroll
  for (int i = 0; i < 8; ++i) acc[i] = (f32x4){0.f, 0.f, 0.f, 0.f};

  for (int s = s0; s < s1; ++s){
    const int k0 = s * BK;
    __syncthreads();   // previous tile's readers done before overwrite

    // Stage A-tile: 64 rows x 64 k, fp32 -> bf16. 1024 float4 chunks, 4/thread.
    // lin: 16 chunks/row -> lanes 0-15 = row 0 (256B contiguous) => coalesced.
    #pragma unroll
    for (int j = 0; j < 4; ++j){
      int lin = tid + j * 256;
      int r   = lin >> 4;
      int c4  = (lin & 15) << 2;
      int gk  = k0 + c4;
      float x0 = 0.f, x1 = 0.f, x2 = 0.f, x3 = 0.f;
      if (gk + 4 <= IN_F){            // K % 4 == 0: chunks are all-or-nothing
        float4 v = *(const float4*)(X + (size_t)(m0 + r) * IN_F + gk);
        x0 = v.x; x1 = v.y; x2 = v.z; x3 = v.w;
      }
      *(uint2*)&As[r * LDS_STRIDE + c4] =
          make_uint2(pack_bf16x2(x0, x1), pack_bf16x2(x2, x3));
    }
    // Stage W-tile: 128 rows x 64 k. 2048 chunks, 8/thread.
    #pragma unroll
    for (int j = 0; j < 8; ++j){
      int lin = tid + j * 256;
      int r   = lin >> 4;
      int c4  = (lin & 15) << 2;
      int gk  = k0 + c4;
      float x0 = 0.f, x1 = 0.f, x2 = 0.f, x3 = 0.f;
      if (gk + 4 <= IN_F){
        float4 v = *(const float4*)(Wg + (size_t)r * IN_F + gk);
        x0 = v.x; x1 = v.y; x2 = v.z; x3 = v.w;
      }
      *(uint2*)&Bs[r * LDS_STRIDE + c4] =
          make_uint2(pack_bf16x2(x0, x1), pack_bf16x2(x2, x3));
    }
    __syncthreads();

    // A-frags: lane holds A[m = wv*16+fr][k = kk*32 + fq*8 + j], j=0..7
    short8 a0 = *(const short8*)&As[(wv * 16 + fr) * LDS_STRIDE + fq * 8];
    short8 a1 = *(const short8*)&As[(wv * 16 + fr) * LDS_STRIDE + 32 + fq * 8];
    #pragma unroll
    for (int nt = 0; nt < 8; ++nt){
      short8 b0 = *(const short8*)&Bs[(nt * 16 + fr) * LDS_STRIDE + fq * 8];
      acc[nt] = __builtin_amdgcn_mfma_f32_16x16x32_bf16(a0, b0, acc[nt], 0, 0, 0);
    }
    #pragma unroll
    for (int nt = 0; nt < 8; ++nt){
      short8 b1 = *(const short8*)&Bs[(nt * 16 + fr) * LDS_STRIDE + 32 + fq * 8];
      acc[nt] = __builtin_amdgcn_mfma_f32_16x16x32_bf16(a1, b1, acc[nt], 0, 0, 0);
    }
  }

  // C/D layout: col = lane&15, row = (lane>>4)*4 + reg  [m89-verified]
  const int rbase = m0 + wv * 16 + fq * 4;
  #pragma unroll
  for (int nt = 0; nt < 8; ++nt){
    int col = nt * 16 + fr;
    #pragma unroll
    for (int r = 0; r < 4; ++r){
      atomicAdd(&accbuf[(size_t)(rbase + r) * NLEAF + col], acc[nt][r]);
    }
  }
}

// In-place: out[idx] holds raw GEMM sum; add bias, hardtanh, then 16-class
// softmax Gini into out[OUT_HALF + idx].
__global__ __launch_bounds__(256)
void epilogue_kernel(float* __restrict__ out,
                     const float* __restrict__ bias,
                     const float* __restrict__ contrib){
  int idx = blockIdx.x * 256 + threadIdx.x;   // < OUT_HALF
  int l   = idx & (NLEAF - 1);
  int row = idx >> 7;
  int t   = row & (NTREES - 1);

  float s = out[idx] + bias[l];
  s = fminf(1.f, fmaxf(-1.f, s));
  out[idx] = s;

  const float4* cp = (const float4*)(contrib + (((size_t)t * NLEAF + l) << 4));
  float4 c0 = cp[0], c1 = cp[1], c2 = cp[2], c3 = cp[3];
  float v[16] = { s*c0.x, s*c0.y, s*c0.z, s*c0.w,
                  s*c1.x, s*c1.y, s*c1.z, s*c1.w,
                  s*c2.x, s*c2.y, s*c2.z, s*c2.w,
                  s*c3.x, s*c3.y, s*c3.z, s*c3.w };
  float m = v[0];
  #pragma unroll
  for (int c = 1; c < 16; ++c) m = fmaxf(m, v[c]);
  float se = 0.f, se2 = 0.f;
  #pragma unroll
  for (int c = 0; c < 16; ++c){
    float e = __expf(v[c] - m);
    se  += e;
    se2 += e * e;
  }
  out[OUT_HALF + idx] = (float)NCLS - se2 / (se * se);
}

extern "C" void kernel_launch(void* const* d_in, const int* in_sizes, int n_in,
                              void* d_out, int out_size, void* d_ws, size_t ws_size,
                              hipStream_t stream){
  const float* X       = (const float*)d_in[0];   // [64,64,16080]
  const float* Wg      = (const float*)d_in[1];   // [128,16080]
  const float* bias    = (const float*)d_in[2];   // [128]
  const float* contrib = (const float*)d_in[3];   // [64,128,16]
  float* out = (float*)d_out;

  // zero the accumulator region (first output half); capturable async memset
  hipMemsetAsync(out, 0, (size_t)OUT_HALF * sizeof(float), stream);

  dim3 g1(M_TOT / BM, KSPLIT);
  gemm_split_kernel<<<g1, 256, 0, stream>>>(X, Wg, out);

  epilogue_kernel<<<OUT_HALF / 256, 256, 0, stream>>>(out, bias, contrib);
}

// Round 3
// 428.981 us; speedup vs baseline: 1.2250x; 1.0351x over previous
//
#include <hip/hip_runtime.h>
#include <hip/hip_bf16.h>
#include <stdint.h>

#define IN_F   16080
#define NTREES 64
#define NLEAF  128
#define NCLS   16
#define NBATCH 64
#define M_TOT  (NBATCH*NTREES)     // 4096
#define OUT_HALF (M_TOT*NLEAF)     // 524288

#define BM 64
#define BN 128
#define BK 64                          // 16 chunks of 4 fp32 per row
#define KSPLIT 16
#define NSTEPS ((IN_F + BK - 1)/BK)    // 252 (251 full + 16-elem tail)

typedef __attribute__((ext_vector_type(8))) short short8;   // 8 x bf16
typedef __attribute__((ext_vector_type(4))) float f32x4;

typedef const __attribute__((address_space(1))) uint32_t gu32_t;
typedef __attribute__((address_space(3))) uint32_t su32_t;

// 8 fp32 -> short8 bf16 frag via packed RNE converts
__device__ __forceinline__ short8 cvt8(float4 lo, float4 hi){
  union { short8 s8; __hip_bfloat162 h2[4]; } u;
  u.h2[0] = __float22bfloat162_rn(make_float2(lo.x, lo.y));
  u.h2[1] = __float22bfloat162_rn(make_float2(lo.z, lo.w));
  u.h2[2] = __float22bfloat162_rn(make_float2(hi.x, hi.y));
  u.h2[3] = __float22bfloat162_rn(make_float2(hi.z, hi.w));
  return u.s8;
}

// C = X[4096,16080] * W[128,16080]^T, split-K partials atomically
// accumulated into accbuf[4096][128] (pre-zeroed).
// B(=W) tile staged fp32 via global_load_lds (XOR-swizzled chunks);
// A fragments loaded straight from global (no cross-wave reuse).
__global__ __launch_bounds__(256, 4)
void gemm_split_kernel(const float* __restrict__ X,
                       const float* __restrict__ Wg,
                       float* __restrict__ accbuf,
                       const float* __restrict__ zeropage){
  __shared__ __align__(16) float BsF[BN * BK];   // 32 KB, fp32, chunk-swizzled

  const int tid = threadIdx.x;
  const int m0  = blockIdx.x * BM;
  const int kc  = blockIdx.y;
  const int s0  = (kc * NSTEPS) / KSPLIT;
  const int s1  = ((kc + 1) * NSTEPS) / KSPLIT;

  const int lane = tid & 63;
  const int wv   = tid >> 6;
  const int wm   = wv & 1;        // 2 m-waves x 2 n-waves
  const int wn   = wv >> 1;
  const int fr   = lane & 15;     // row/col within 16x16 tile
  const int fq   = lane >> 4;     // k-quad

  f32x4 acc[2][4];
  #pragma unroll
  for (int mt = 0; mt < 2; ++mt)
    #pragma unroll
    for (int nt = 0; nt < 4; ++nt) acc[mt][nt] = (f32x4){0.f,0.f,0.f,0.f};

  // staging lane constants
  // B: 2048 chunks (128 rows x 16), 8 per thread; LDS pos lin, global chunk c = p ^ (r&7)
  for (int s = s0; s < s1; ++s){
    const int k0 = s * BK;
    __syncthreads();   // previous tile's ds_read consumers done

    // --- A fragments: direct global -> regs (2 mt x 2 halves x 2 quads) ---
    float4 av[2][2][2];
    #pragma unroll
    for (int mt = 0; mt < 2; ++mt){
      const float* rowp = X + (size_t)(m0 + wm*32 + mt*16 + fr) * IN_F;
      #pragma unroll
      for (int h = 0; h < 2; ++h)
        #pragma unroll
        for (int q = 0; q < 2; ++q){
          int gk = k0 + h*32 + fq*8 + q*4;
          av[mt][h][q] = (gk + 4 <= IN_F) ? *(const float4*)(rowp + gk)
                                          : make_float4(0.f,0.f,0.f,0.f);
        }
    }

    // --- B tile: 8 global_load_lds dwordx4, fp32, swizzled chunk gather ---
    #pragma unroll
    for (int j = 0; j < 8; ++j){
      int lin = j*256 + tid;
      int r   = lin >> 4;
      int p   = lin & 15;
      int c   = p ^ (r & 7);
      int gk  = k0 + c*4;
      const float* gp = (gk + 4 <= IN_F) ? (Wg + (size_t)r * IN_F + gk)
                                         : zeropage;
      __builtin_amdgcn_global_load_lds((gu32_t*)gp, (su32_t*)(BsF + lin*4),
                                       16, 0, 0);
    }

    // convert A while B loads are in flight
    short8 af[2][2];
    #pragma unroll
    for (int mt = 0; mt < 2; ++mt)
      #pragma unroll
      for (int h = 0; h < 2; ++h)
        af[mt][h] = cvt8(av[mt][h][0], av[mt][h][1]);

    __syncthreads();   // drains vmcnt(0): B tile resident in LDS

    // --- compute: 4 nt x 2 halves x 2 mt MFMAs ---
    #pragma unroll
    for (int nt = 0; nt < 4; ++nt){
      const int l  = wn*64 + nt*16 + fr;
      const int xw = l & 7;
      const float* rowb = BsF + l*64;     // 16 chunks of 4 fp32
      #pragma unroll
      for (int h = 0; h < 2; ++h){
        int c0 = h*8 + fq*2;
        float4 b0 = *(const float4*)(rowb + ((c0    ) ^ xw)*4);
        float4 b1 = *(const float4*)(rowb + ((c0 + 1) ^ xw)*4);
        short8 bf = cvt8(b0, b1);
        #pragma unroll
        for (int mt = 0; mt < 2; ++mt)
          acc[mt][nt] = __builtin_amdgcn_mfma_f32_16x16x32_bf16(
                            af[mt][h], bf, acc[mt][nt], 0, 0, 0);
      }
    }
  }

  // C/D layout: col = lane&15, row = (lane>>4)*4 + reg  [m89-verified]
  #pragma unroll
  for (int mt = 0; mt < 2; ++mt){
    const int rbase = m0 + wm*32 + mt*16 + fq*4;
    #pragma unroll
    for (int nt = 0; nt < 4; ++nt){
      int col = wn*64 + nt*16 + fr;
      #pragma unroll
      for (int r = 0; r < 4; ++r)
        atomicAdd(&accbuf[(size_t)(rbase + r) * NLEAF + col], acc[mt][nt][r]);
    }
  }
}

// In-place: out[idx] holds raw GEMM sum; add bias, hardtanh, then 16-class
// softmax Gini into out[OUT_HALF + idx].
__global__ __launch_bounds__(256)
void epilogue_kernel(float* __restrict__ out,
                     const float* __restrict__ bias,
                     const float* __restrict__ contrib){
  int idx = blockIdx.x * 256 + threadIdx.x;   // < OUT_HALF
  int l   = idx & (NLEAF - 1);
  int row = idx >> 7;
  int t   = row & (NTREES - 1);

  float s = out[idx] + bias[l];
  s = fminf(1.f, fmaxf(-1.f, s));
  out[idx] = s;

  const float4* cp = (const float4*)(contrib + (((size_t)t * NLEAF + l) << 4));
  float4 c0 = cp[0], c1 = cp[1], c2 = cp[2], c3 = cp[3];
  float v[16] = { s*c0.x, s*c0.y, s*c0.z, s*c0.w,
                  s*c1.x, s*c1.y, s*c1.z, s*c1.w,
                  s*c2.x, s*c2.y, s*c2.z, s*c2.w,
                  s*c3.x, s*c3.y, s*c3.z, s*c3.w };
  float m = v[0];
  #pragma unroll
  for (int c = 1; c < 16; ++c) m = fmaxf(m, v[c]);
  float se = 0.f, se2 = 0.f;
  #pragma unroll
  for (int c = 0; c < 16; ++c){
    float e = __expf(v[c] - m);
    se  += e;
    se2 += e * e;
  }
  out[OUT_HALF + idx] = (float)NCLS - se2 / (se * se);
}

extern "C" void kernel_launch(void* const* d_in, const int* in_sizes, int n_in,
                              void* d_out, int out_size, void* d_ws, size_t ws_size,
                              hipStream_t stream){
  const float* X       = (const float*)d_in[0];   // [64,64,16080]
  const float* Wg      = (const float*)d_in[1];   // [128,16080]
  const float* bias    = (const float*)d_in[2];   // [128]
  const float* contrib = (const float*)d_in[3];   // [64,128,16]
  float* out = (float*)d_out;

  // zero GEMM accumulator (first output half) + a 256B zero page in d_ws
  // (OOB K-tail lanes of global_load_lds redirect here)
  hipMemsetAsync(out, 0, (size_t)OUT_HALF * sizeof(float), stream);
  hipMemsetAsync(d_ws, 0, 256, stream);

  dim3 g1(M_TOT / BM, KSPLIT);
  gemm_split_kernel<<<g1, 256, 0, stream>>>(X, Wg, out, (const float*)d_ws);

  epilogue_kernel<<<OUT_HALF / 256, 256, 0, stream>>>(out, bias, contrib);
}